// Round 4
// baseline (2659.606 us; speedup 1.0000x reference)
//
#include <hip/hip_runtime.h>

#define RNN_T 2048
#define RNN_B 64
#define RNN_H 256

typedef float v2f __attribute__((ext_vector_type(2)));

// ---------------------------------------------------------------------------
// Kernel 1: xproj[b,t,:] = embed[x[b,t]] @ Wx + b_fc   (written into hs region)
// ---------------------------------------------------------------------------
__global__ __launch_bounds__(256)
void xproj_kernel(const int* __restrict__ x, const float* __restrict__ embed,
                  const float* __restrict__ Wfc, const float* __restrict__ bfc,
                  float* __restrict__ hsb) {
    __shared__ int ixs[64];
    __shared__ __align__(16) float A[64][260];
    const int tid = threadIdx.x;
    const long rb0 = (long)blockIdx.x * 64;

    if (tid < 64) ixs[tid] = x[rb0 + tid];
    __syncthreads();

    {   // stage 64 gathered embed rows: 4 threads per row, 16 float4 each
        const int r = tid >> 2, q = tid & 3;
        const float* erow = embed + (long)ixs[r] * RNN_H;
        #pragma unroll
        for (int i = 0; i < 16; ++i) {
            const int c = q * 64 + i * 4;
            *(float4*)&A[r][c] = *(const float4*)(erow + c);
        }
    }
    __syncthreads();

    const int tj = tid & 31, tr = tid >> 5;
    const int r0 = tr * 8, j0 = tj * 4, j1 = 128 + tj * 4;

    float acc[8][8];
    #pragma unroll
    for (int i = 0; i < 8; ++i)
        #pragma unroll
        for (int c = 0; c < 8; ++c) acc[i][c] = 0.f;

    for (int k4 = 0; k4 < 64; ++k4) {
        float4 a[8];
        #pragma unroll
        for (int i = 0; i < 8; ++i) a[i] = *(const float4*)&A[r0 + i][k4 * 4];
        #pragma unroll
        for (int kk = 0; kk < 4; ++kk) {
            const int k = k4 * 4 + kk;
            const float4 wa = *(const float4*)(Wfc + (long)k * RNN_H + j0);
            const float4 wb = *(const float4*)(Wfc + (long)k * RNN_H + j1);
            #pragma unroll
            for (int i = 0; i < 8; ++i) {
                const float av = reinterpret_cast<const float*>(&a[i])[kk];
                acc[i][0] = fmaf(av, wa.x, acc[i][0]);
                acc[i][1] = fmaf(av, wa.y, acc[i][1]);
                acc[i][2] = fmaf(av, wa.z, acc[i][2]);
                acc[i][3] = fmaf(av, wa.w, acc[i][3]);
                acc[i][4] = fmaf(av, wb.x, acc[i][4]);
                acc[i][5] = fmaf(av, wb.y, acc[i][5]);
                acc[i][6] = fmaf(av, wb.z, acc[i][6]);
                acc[i][7] = fmaf(av, wb.w, acc[i][7]);
            }
        }
    }

    const float4 ba = *(const float4*)(bfc + j0);
    const float4 bb = *(const float4*)(bfc + j1);
    #pragma unroll
    for (int i = 0; i < 8; ++i) {
        const long row = rb0 + r0 + i;
        float4 o1 = make_float4(acc[i][0] + ba.x, acc[i][1] + ba.y,
                                acc[i][2] + ba.z, acc[i][3] + ba.w);
        float4 o2 = make_float4(acc[i][4] + bb.x, acc[i][5] + bb.y,
                                acc[i][6] + bb.z, acc[i][7] + bb.w);
        *(float4*)(hsb + row * RNN_H + j0) = o1;
        *(float4*)(hsb + row * RNN_H + j1) = o2;
    }
}

// ---------------------------------------------------------------------------
// Kernel 2: persistent RNN scan. One WG per batch row, 256 threads (4 waves).
// Wave w (0..3), lane l: column base jc = w*16 + (l&15); thread owns columns
// jc+{0,64,128,192} and k-segment ks = l>>4 (64 rows). Weights: 128 float2
// per thread (static indices only; bank-rotation baked into load perm).
// Inner product via packed v_pk_fma_f32 (__builtin_elementwise_fma on v2f):
// 128 pk-FMA/step/thread. h broadcast from LDS: 16 ds_read_b128/thread,
// each reused 8x (4 cols x 2 pairs). 1 wave/SIMD -> 512-VGPR budget.
// In-wave 4-seg reduce (shfl_xor 16,32); h double-buffered; 1 barrier/step.
// 2-deep xproj prefetch (HBM latency ~375ns > step time).
// ---------------------------------------------------------------------------
__global__ __launch_bounds__(256, 1)
void rnn_scan_kernel(const float* __restrict__ Wfc, const float* __restrict__ Wout,
                     const float* __restrict__ bout, float* __restrict__ out,
                     float* __restrict__ hsb) {
    __shared__ __align__(16) float hbuf[2][RNN_H];
    const int tid = threadIdx.x;
    const int b = blockIdx.x;
    const int w = tid >> 6, l = tid & 63;
    const int jc = w * 16 + (l & 15);
    const int ks = l >> 4;              // 0..3
    const int k0 = ks * 64;

    // --- load Wh slice: wp[c][i4*2+p] = Wh[k0 + r*4 + 2p .. +1][jc + 64c],
    //     r = (i4 + 2*ks) & 15 baked in at load time (compute side stays static)
    const float* Wh = Wfc + RNN_H * RNN_H;
    v2f wp[4][32];
    #pragma unroll
    for (int i4 = 0; i4 < 16; ++i4) {
        const int r = (i4 + 2 * ks) & 15;
        #pragma unroll
        for (int p = 0; p < 2; ++p) {
            const long kbase = (long)(k0 + r * 4 + 2 * p) * RNN_H;
            #pragma unroll
            for (int c = 0; c < 4; ++c) {
                v2f t;
                t.x = Wh[kbase + jc + 64 * c];
                t.y = Wh[kbase + RNN_H + jc + 64 * c];
                wp[c][i4 * 2 + p] = t;
            }
        }
    }
    #pragma unroll
    for (int i = 0; i < 32; ++i) {
        asm volatile("" : "+v"(wp[0][i]), "+v"(wp[1][i]), "+v"(wp[2][i]), "+v"(wp[3][i]));
    }

    hbuf[0][tid] = 0.f;

    float* xpb = hsb + (long)b * RNN_T * RNN_H;
    const bool lead = (l < 16);
    float xr[4] = {0,0,0,0}, xn[4] = {0,0,0,0};
    if (lead) {
        #pragma unroll
        for (int c = 0; c < 4; ++c) {
            xr[c] = xpb[jc + 64 * c];
            xn[c] = xpb[RNN_H + jc + 64 * c];
        }
    }
    __syncthreads();

    int cur = 0;
    for (int t = 0; t < RNN_T; ++t) {
        float xf[4] = {0,0,0,0};
        if (lead && t + 2 < RNN_T) {             // 2-deep prefetch
            #pragma unroll
            for (int c = 0; c < 4; ++c)
                xf[c] = xpb[(long)(t + 2) * RNN_H + jc + 64 * c];
        }

        const float4* h4 = (const float4*)hbuf[cur];
        v2f acc[4];
        #pragma unroll
        for (int c = 0; c < 4; ++c) acc[c] = (v2f){0.f, 0.f};

        #pragma unroll
        for (int i4 = 0; i4 < 16; ++i4) {
            const int r = (i4 + 2 * ks) & 15;    // runtime -> LDS ADDRESS only
            const float4 hv = h4[ks * 16 + r];   // broadcast within 16-lane grp
            const v2f ha = {hv.x, hv.y};
            const v2f hb = {hv.z, hv.w};
            #pragma unroll
            for (int c = 0; c < 4; ++c) {        // static reg indices everywhere
                acc[c] = __builtin_elementwise_fma(ha, wp[c][i4 * 2 + 0], acc[c]);
                acc[c] = __builtin_elementwise_fma(hb, wp[c][i4 * 2 + 1], acc[c]);
            }
        }

        float s[4];
        #pragma unroll
        for (int c = 0; c < 4; ++c) {
            s[c] = acc[c].x + acc[c].y;
            s[c] += __shfl_xor(s[c], 16);        // reduce 4 k-segments
            s[c] += __shfl_xor(s[c], 32);
        }

        if (lead) {
            #pragma unroll
            for (int c = 0; c < 4; ++c) {
                const float v = s[c] + xr[c];
                const float e = __expf(2.f * v);
                const float hn = 1.f - 2.f * __builtin_amdgcn_rcpf(e + 1.f);
                hbuf[cur ^ 1][jc + 64 * c] = hn;
                xpb[(long)t * RNN_H + jc + 64 * c] = hn;   // hs output
                xr[c] = xn[c];
                xn[c] = xf[c];
            }
        }
        __syncthreads();
        cur ^= 1;
    }

    // epilogue: out[b,:] = h_last @ W_out + b_out  (256 threads = 256 cols)
    {
        const float* hl = hbuf[cur];
        float a0 = 0.f, a1 = 0.f, a2 = 0.f, a3 = 0.f;
        for (int k = 0; k < RNN_H; k += 4) {
            a0 = fmaf(hl[k + 0], Wout[(long)(k + 0) * RNN_H + tid], a0);
            a1 = fmaf(hl[k + 1], Wout[(long)(k + 1) * RNN_H + tid], a1);
            a2 = fmaf(hl[k + 2], Wout[(long)(k + 2) * RNN_H + tid], a2);
            a3 = fmaf(hl[k + 3], Wout[(long)(k + 3) * RNN_H + tid], a3);
        }
        out[(long)b * RNN_H + tid] = a0 + a1 + a2 + a3 + bout[tid];
    }
}

extern "C" void kernel_launch(void* const* d_in, const int* in_sizes, int n_in,
                              void* d_out, int out_size, void* d_ws, size_t ws_size,
                              hipStream_t stream) {
    const int*   x     = (const int*)d_in[0];
    const float* embed = (const float*)d_in[1];
    const float* Wfc   = (const float*)d_in[2];
    const float* bfc   = (const float*)d_in[3];
    const float* Wout  = (const float*)d_in[4];
    const float* bout  = (const float*)d_in[5];

    float* out = (float*)d_out;                 // [B, 256]
    float* hsb = out + RNN_B * RNN_H;           // [B, T, H] region

    xproj_kernel<<<(RNN_B * RNN_T) / 64, 256, 0, stream>>>(x, embed, Wfc, bfc, hsb);
    rnn_scan_kernel<<<RNN_B, 256, 0, stream>>>(Wfc, Wout, bout, out, hsb);
}

// Round 5
// 1827.702 us; speedup vs baseline: 1.4552x; 1.4552x over previous
//
#include <hip/hip_runtime.h>

#define RNN_T 2048
#define RNN_B 64
#define RNN_H 256
#define SEG 68   // padded k-segment stride (floats): 4 groups -> disjoint banks

typedef float v2f __attribute__((ext_vector_type(2)));

// ---------------------------------------------------------------------------
// Kernel 1: xproj[b,t,:] = embed[x[b,t]] @ Wx + b_fc   (written into hs region)
// ---------------------------------------------------------------------------
__global__ __launch_bounds__(256)
void xproj_kernel(const int* __restrict__ x, const float* __restrict__ embed,
                  const float* __restrict__ Wfc, const float* __restrict__ bfc,
                  float* __restrict__ hsb) {
    __shared__ int ixs[64];
    __shared__ __align__(16) float A[64][260];
    const int tid = threadIdx.x;
    const long rb0 = (long)blockIdx.x * 64;

    if (tid < 64) ixs[tid] = x[rb0 + tid];
    __syncthreads();

    {   // stage 64 gathered embed rows: 4 threads per row, 16 float4 each
        const int r = tid >> 2, q = tid & 3;
        const float* erow = embed + (long)ixs[r] * RNN_H;
        #pragma unroll
        for (int i = 0; i < 16; ++i) {
            const int c = q * 64 + i * 4;
            *(float4*)&A[r][c] = *(const float4*)(erow + c);
        }
    }
    __syncthreads();

    const int tj = tid & 31, tr = tid >> 5;
    const int r0 = tr * 8, j0 = tj * 4, j1 = 128 + tj * 4;

    float acc[8][8];
    #pragma unroll
    for (int i = 0; i < 8; ++i)
        #pragma unroll
        for (int c = 0; c < 8; ++c) acc[i][c] = 0.f;

    for (int k4 = 0; k4 < 64; ++k4) {
        float4 a[8];
        #pragma unroll
        for (int i = 0; i < 8; ++i) a[i] = *(const float4*)&A[r0 + i][k4 * 4];
        #pragma unroll
        for (int kk = 0; kk < 4; ++kk) {
            const int k = k4 * 4 + kk;
            const float4 wa = *(const float4*)(Wfc + (long)k * RNN_H + j0);
            const float4 wb = *(const float4*)(Wfc + (long)k * RNN_H + j1);
            #pragma unroll
            for (int i = 0; i < 8; ++i) {
                const float av = reinterpret_cast<const float*>(&a[i])[kk];
                acc[i][0] = fmaf(av, wa.x, acc[i][0]);
                acc[i][1] = fmaf(av, wa.y, acc[i][1]);
                acc[i][2] = fmaf(av, wa.z, acc[i][2]);
                acc[i][3] = fmaf(av, wa.w, acc[i][3]);
                acc[i][4] = fmaf(av, wb.x, acc[i][4]);
                acc[i][5] = fmaf(av, wb.y, acc[i][5]);
                acc[i][6] = fmaf(av, wb.z, acc[i][6]);
                acc[i][7] = fmaf(av, wb.w, acc[i][7]);
            }
        }
    }

    const float4 ba = *(const float4*)(bfc + j0);
    const float4 bb = *(const float4*)(bfc + j1);
    #pragma unroll
    for (int i = 0; i < 8; ++i) {
        const long row = rb0 + r0 + i;
        float4 o1 = make_float4(acc[i][0] + ba.x, acc[i][1] + ba.y,
                                acc[i][2] + ba.z, acc[i][3] + ba.w);
        float4 o2 = make_float4(acc[i][4] + bb.x, acc[i][5] + bb.y,
                                acc[i][6] + bb.z, acc[i][7] + bb.w);
        *(float4*)(hsb + row * RNN_H + j0) = o1;
        *(float4*)(hsb + row * RNN_H + j1) = o2;
    }
}

// ---------------------------------------------------------------------------
// Kernel 2: persistent RNN scan. One WG per batch row, 1024 threads
// (16 waves = exactly 4 waves/SIMD -> arch-VGPR cap 128, real TLP).
// Thread (w,l): column jc = w*16 + (l&15), k-segment ks = l>>4 (64 rows).
// Per-thread weights: 64 floats = 32 v2f -> ~105 total VGPRs < 128 cap, so
// the allocator keeps them in ARCH VGPRs (R1/R3/R4 lesson: >256-arch-VGPR
// footprints get shelved in AGPRs with per-step v_accvgpr_read traffic).
// All register indices compile-time static (rule #20). h in LDS with padded
// segment stride 68 -> the 4 k-groups of a wave read disjoint 4-bank windows.
// In-wave k-reduce (shfl_xor 16,32); h double-buffered; ONE barrier/step.
// ---------------------------------------------------------------------------
__global__ __launch_bounds__(1024, 4)
void rnn_scan_kernel(const float* __restrict__ Wfc, const float* __restrict__ Wout,
                     const float* __restrict__ bout, float* __restrict__ out,
                     float* __restrict__ hsb) {
    __shared__ __align__(16) float hbuf[2][4 * SEG];
    const int tid = threadIdx.x;
    const int b = blockIdx.x;
    const int w = tid >> 6, l = tid & 63;
    const int jc = w * 16 + (l & 15);   // column 0..255
    const int ks = l >> 4;              // k-segment 0..3
    const int k0 = ks * 64;

    // --- load 64 weights: wv[2*i4+p] = {Wh[k0+4i4+2p][jc], Wh[k0+4i4+2p+1][jc]}
    const float* Wh = Wfc + RNN_H * RNN_H;
    v2f wv[32];
    #pragma unroll
    for (int i4 = 0; i4 < 16; ++i4) {
        #pragma unroll
        for (int p = 0; p < 2; ++p) {
            v2f t;
            t.x = Wh[(long)(k0 + i4 * 4 + 2 * p) * RNN_H + jc];
            t.y = Wh[(long)(k0 + i4 * 4 + 2 * p + 1) * RNN_H + jc];
            wv[i4 * 2 + p] = t;
        }
    }
    #pragma unroll
    for (int i = 0; i < 32; ++i) asm volatile("" : "+v"(wv[i]));  // no remat

    if (tid < 4 * SEG) hbuf[0][tid] = 0.f;

    float* xpb = hsb + (long)b * RNN_T * RNN_H;
    const bool lead = (l < 16);
    float xr = 0.f, xn = 0.f;
    if (lead) {
        xr = xpb[jc];
        xn = xpb[RNN_H + jc];
    }
    __syncthreads();

    int cur = 0;
    for (int t = 0; t < RNN_T; ++t) {
        float xf = 0.f;
        if (lead && t + 2 < RNN_T)                  // 2-deep prefetch
            xf = xpb[(long)(t + 2) * RNN_H + jc];

        // h segment reads: byte base = ks*SEG*4 = ks*272 (16B aligned)
        const float4* h4 = (const float4*)(hbuf[cur] + ks * SEG);
        v2f a0 = {0.f, 0.f}, a1 = {0.f, 0.f};      // 2 ILP chains
        #pragma unroll
        for (int i = 0; i < 16; ++i) {
            const float4 hv = h4[i];               // broadcast in 16-lane group
            const v2f ha = {hv.x, hv.y};
            const v2f hb = {hv.z, hv.w};
            if (i & 1) {
                a1 = __builtin_elementwise_fma(ha, wv[i * 2 + 0], a1);
                a1 = __builtin_elementwise_fma(hb, wv[i * 2 + 1], a1);
            } else {
                a0 = __builtin_elementwise_fma(ha, wv[i * 2 + 0], a0);
                a0 = __builtin_elementwise_fma(hb, wv[i * 2 + 1], a0);
            }
        }
        float s = a0.x + a0.y + a1.x + a1.y;
        s += __shfl_xor(s, 16);                    // reduce 4 k-segments
        s += __shfl_xor(s, 32);

        if (lead) {
            const float v = s + xr;
            const float e = __expf(2.f * v);
            const float hn = 1.f - 2.f * __builtin_amdgcn_rcpf(e + 1.f);  // tanh
            hbuf[cur ^ 1][(jc >> 6) * SEG + (jc & 63)] = hn;
            xpb[(long)t * RNN_H + jc] = hn;        // hs output
            xr = xn;
            xn = xf;
        }
        __syncthreads();
        cur ^= 1;
    }

    // epilogue: out[b,:] = h_last @ W_out + b_out  (first 256 threads)
    if (tid < RNN_H) {
        const float* hl = hbuf[cur];
        float a0 = 0.f, a1 = 0.f, a2 = 0.f, a3 = 0.f;
        for (int k = 0; k < RNN_H; k += 4) {
            const int kb = (k >> 6) * SEG + (k & 63);
            a0 = fmaf(hl[kb + 0], Wout[(long)(k + 0) * RNN_H + tid], a0);
            a1 = fmaf(hl[kb + 1], Wout[(long)(k + 1) * RNN_H + tid], a1);
            a2 = fmaf(hl[kb + 2], Wout[(long)(k + 2) * RNN_H + tid], a2);
            a3 = fmaf(hl[kb + 3], Wout[(long)(k + 3) * RNN_H + tid], a3);
        }
        out[(long)b * RNN_H + tid] = a0 + a1 + a2 + a3 + bout[tid];
    }
}

extern "C" void kernel_launch(void* const* d_in, const int* in_sizes, int n_in,
                              void* d_out, int out_size, void* d_ws, size_t ws_size,
                              hipStream_t stream) {
    const int*   x     = (const int*)d_in[0];
    const float* embed = (const float*)d_in[1];
    const float* Wfc   = (const float*)d_in[2];
    const float* bfc   = (const float*)d_in[3];
    const float* Wout  = (const float*)d_in[4];
    const float* bout  = (const float*)d_in[5];

    float* out = (float*)d_out;                 // [B, 256]
    float* hsb = out + RNN_B * RNN_H;           // [B, T, H] region

    xproj_kernel<<<(RNN_B * RNN_T) / 64, 256, 0, stream>>>(x, embed, Wfc, bfc, hsb);
    rnn_scan_kernel<<<RNN_B, 1024, 0, stream>>>(Wfc, Wout, bout, out, hsb);
}